// Round 2
// baseline (912.872 us; speedup 1.0000x reference)
//
#include <hip/hip_runtime.h>

#define DIM   512
#define LSEQ  4096
#define BATCH 8
#define NTOK  (BATCH * LSEQ)   // 32768
#define NCHUNK 4
#define MCH   (NTOK / NCHUNK)  // 8192 tokens per chunk

typedef __bf16 bf16_t;
typedef bf16_t bf16x8 __attribute__((ext_vector_type(8)));
typedef float  f32x4  __attribute__((ext_vector_type(4)));

__device__ __forceinline__ unsigned short f2bf(float f) {
  unsigned u = __builtin_bit_cast(unsigned, f);
  unsigned r = u + 0x7fffu + ((u >> 16) & 1u);   // RNE
  return (unsigned short)(r >> 16);
}
__device__ __forceinline__ float bf2f(unsigned short s) {
  return __builtin_bit_cast(float, ((unsigned)s) << 16);
}
__device__ __forceinline__ bf16x8 ld_frag(const unsigned short* p) {
  uint4 v = *reinterpret_cast<const uint4*>(p);
  return __builtin_bit_cast(bf16x8, v);
}

// ---------------- transpose: in[B][R][C] f32 -> out[B][C][R] (f32 or bf16)
template <bool OUT_BF16>
__global__ __launch_bounds__(256) void transpose_kernel(
    const float* __restrict__ in, void* __restrict__ out, int R, int C) {
  __shared__ float tile[64][65];
  const int b = blockIdx.z;
  const int r0 = blockIdx.y * 64, c0 = blockIdx.x * 64;
  const float* ip = in + ((size_t)b * R + r0) * C + c0;
#pragma unroll
  for (int i = 0; i < 16; ++i) {
    int flat = i * 256 + threadIdx.x;
    int r = flat >> 6, c = flat & 63;
    tile[r][c] = ip[(size_t)r * C + c];
  }
  __syncthreads();
#pragma unroll
  for (int i = 0; i < 16; ++i) {
    int flat = i * 256 + threadIdx.x;
    int r = flat >> 6, c = flat & 63;   // r = col-of-input
    size_t idx = ((size_t)b * C + c0 + r) * R + r0 + c;
    if constexpr (OUT_BF16)
      reinterpret_cast<unsigned short*>(out)[idx] = f2bf(tile[c][r]);
    else
      reinterpret_cast<float*>(out)[idx] = tile[c][r];
  }
}

// ---------------- GEMM: C = A[MxK](bf16) @ W[KxN](f32) + bias
//                  optionally (*scale + bias2 + res). Out bf16.
template <bool SCALERES>
__global__ __launch_bounds__(256) void gemm_kernel(
    const unsigned short* __restrict__ A, const float* __restrict__ W,
    const float* __restrict__ bias, const float* __restrict__ scale,
    const float* __restrict__ bias2, const unsigned short* __restrict__ res,
    unsigned short* __restrict__ Cout, int M, int N, int K) {
  __shared__ unsigned short As[128 * 64];  // [row][k] swizzled
  __shared__ unsigned short Bs[128 * 64];  // [n][k]  swizzled
  const int tid = threadIdx.x;
  const int lane = tid & 63;
  const int wave = tid >> 6;
  const int wm = wave >> 1, wn = wave & 1;
  const int row0 = blockIdx.y * 128, col0 = blockIdx.x * 128;

  f32x4 acc[4][4] = {};

  for (int kt = 0; kt < K; kt += 64) {
    // ---- stage A tile (128 x 64 bf16) ----
#pragma unroll
    for (int i = 0; i < 4; ++i) {
      int flat = i * 2048 + tid * 8;
      int r = flat >> 6, k = flat & 63;
      const uint4 v = *reinterpret_cast<const uint4*>(
          A + (size_t)(row0 + r) * K + kt + k);
      *reinterpret_cast<uint4*>(&As[r * 64 + (k ^ ((r & 7) << 3))]) = v;
    }
    // ---- stage B tile (64 k x 128 n f32), transposed into [n][k] ----
#pragma unroll
    for (int i = 0; i < 8; ++i) {
      int flat = i * 1024 + tid * 4;
      int k = flat >> 7, n = flat & 127;
      const float4 v = *reinterpret_cast<const float4*>(
          W + (size_t)(kt + k) * N + col0 + n);
      float vv[4] = {v.x, v.y, v.z, v.w};
#pragma unroll
      for (int j = 0; j < 4; ++j) {
        int nn = n + j;
        Bs[nn * 64 + (k ^ ((nn & 7) << 3))] = f2bf(vv[j]);
      }
    }
    __syncthreads();
    // ---- compute ----
#pragma unroll
    for (int kk = 0; kk < 64; kk += 32) {
      const int kb = kk + (lane >> 4) * 8;
      bf16x8 af[4], bfr[4];
#pragma unroll
      for (int m = 0; m < 4; ++m) {
        int r = wm * 64 + m * 16 + (lane & 15);
        af[m] = ld_frag(&As[r * 64 + (kb ^ ((r & 7) << 3))]);
      }
#pragma unroll
      for (int n = 0; n < 4; ++n) {
        int r = wn * 64 + n * 16 + (lane & 15);
        bfr[n] = ld_frag(&Bs[r * 64 + (kb ^ ((r & 7) << 3))]);
      }
#pragma unroll
      for (int m = 0; m < 4; ++m)
#pragma unroll
        for (int n = 0; n < 4; ++n)
          acc[m][n] = __builtin_amdgcn_mfma_f32_16x16x32_bf16(
              af[m], bfr[n], acc[m][n], 0, 0, 0);
    }
    __syncthreads();
  }
  // ---- epilogue ----
#pragma unroll
  for (int m = 0; m < 4; ++m) {
#pragma unroll
    for (int n = 0; n < 4; ++n) {
      const int col = col0 + wn * 64 + n * 16 + (lane & 15);
      const float b1 = bias[col];
      float sc = 1.f, b2 = 0.f;
      if constexpr (SCALERES) { sc = scale[col]; b2 = bias2[col]; }
#pragma unroll
      for (int r = 0; r < 4; ++r) {
        const int row = row0 + wm * 64 + m * 16 + (lane >> 4) * 4 + r;
        float v = acc[m][n][r] + b1;
        if constexpr (SCALERES) {
          v = v * sc + b2;
          v += bf2f(res[(size_t)row * N + col]);
        }
        Cout[(size_t)row * N + col] = f2bf(v);
      }
    }
  }
}

// ---------------- FFN1 + GLU fused: g = (h@W1+b1)[:, :1024] * silu(...[:,1024:])
// Block computes g rows [row0,row0+128) x g-cols [c0, c0+64).
// B-row r -> gcol = (r>>6)*32 + ((r>>4)&1)*16 + (r&15), isGate = (r>>5)&1
__global__ __launch_bounds__(256) void ffn1glu_kernel(
    const unsigned short* __restrict__ A, const float* __restrict__ W1,
    const float* __restrict__ b1, unsigned short* __restrict__ g) {
  __shared__ unsigned short As[128 * 64];
  __shared__ unsigned short Bs[128 * 64];
  const int tid = threadIdx.x;
  const int lane = tid & 63;
  const int wave = tid >> 6;
  const int wm = wave >> 1, wn = wave & 1;
  const int row0 = blockIdx.y * 128, c0 = blockIdx.x * 64;
  const int K = 512, NW = 2048;

  f32x4 acc[4][4] = {};

  for (int kt = 0; kt < K; kt += 64) {
#pragma unroll
    for (int i = 0; i < 4; ++i) {
      int flat = i * 2048 + tid * 8;
      int r = flat >> 6, k = flat & 63;
      const uint4 v = *reinterpret_cast<const uint4*>(
          A + (size_t)(row0 + r) * K + kt + k);
      *reinterpret_cast<uint4*>(&As[r * 64 + (k ^ ((r & 7) << 3))]) = v;
    }
#pragma unroll
    for (int i = 0; i < 8; ++i) {
      int flat = i * 1024 + tid * 4;
      int k = flat >> 7, n = flat & 127;
      int gcol = ((n >> 6) << 5) + (((n >> 4) & 1) << 4) + (n & 15);
      int wcol = ((n >> 5) & 1) * 1024 + c0 + gcol;
      const float4 v = *reinterpret_cast<const float4*>(
          W1 + (size_t)(kt + k) * NW + wcol);
      float vv[4] = {v.x, v.y, v.z, v.w};
#pragma unroll
      for (int j = 0; j < 4; ++j) {
        int nn = n + j;
        Bs[nn * 64 + (k ^ ((nn & 7) << 3))] = f2bf(vv[j]);
      }
    }
    __syncthreads();
#pragma unroll
    for (int kk = 0; kk < 64; kk += 32) {
      const int kb = kk + (lane >> 4) * 8;
      bf16x8 af[4], bfr[4];
#pragma unroll
      for (int m = 0; m < 4; ++m) {
        int r = wm * 64 + m * 16 + (lane & 15);
        af[m] = ld_frag(&As[r * 64 + (kb ^ ((r & 7) << 3))]);
      }
#pragma unroll
      for (int n = 0; n < 4; ++n) {
        int r = wn * 64 + n * 16 + (lane & 15);
        bfr[n] = ld_frag(&Bs[r * 64 + (kb ^ ((r & 7) << 3))]);
      }
#pragma unroll
      for (int m = 0; m < 4; ++m)
#pragma unroll
        for (int n = 0; n < 4; ++n)
          acc[m][n] = __builtin_amdgcn_mfma_f32_16x16x32_bf16(
              af[m], bfr[n], acc[m][n], 0, 0, 0);
    }
    __syncthreads();
  }
  // epilogue: pair acc[m][n] (out) with acc[m][n+2] (gate), n in {0,1}
#pragma unroll
  for (int m = 0; m < 4; ++m) {
#pragma unroll
    for (int n = 0; n < 2; ++n) {
      const int gc = c0 + wn * 32 + n * 16 + (lane & 15);
      const float bo = b1[gc];
      const float bg = b1[1024 + gc];
#pragma unroll
      for (int r = 0; r < 4; ++r) {
        const int row = row0 + wm * 64 + m * 16 + (lane >> 4) * 4 + r;
        float o  = acc[m][n][r] + bo;
        float ga = acc[m][n + 2][r] + bg;
        float s  = ga / (1.f + __expf(-ga));
        g[(size_t)row * 1024 + gc] = f2bf(o * s);
      }
    }
  }
}

// ---------------- block-local attention, one (blk-of-64-tokens, head) per WG
// qkv: [MCH][1536] bf16, per-head [q64|k64|v64]. out: [MCH][512] bf16
__global__ __launch_bounds__(256) void attn_kernel(
    const unsigned short* __restrict__ qkv, unsigned short* __restrict__ out) {
  __shared__ unsigned short Qs[64 * 64];  // [q][d]
  __shared__ unsigned short Ks[64 * 64];  // [kkey][d]
  __shared__ unsigned short Vs[64 * 64];  // [d][key]  (transposed)
  __shared__ unsigned short Ps[64 * 64];  // [q][key]
  const int id = blockIdx.x;
  const int h = id & 7, blk = id >> 3;    // blk 0..127 within chunk
  const size_t tok0 = (size_t)blk * 64;
  const unsigned short* base = qkv + tok0 * 1536 + h * 192;
  const int tid = threadIdx.x, lane = tid & 63, wave = tid >> 6;

#pragma unroll
  for (int i = 0; i < 2; ++i) {
    int flat = i * 2048 + tid * 8;
    int r = flat >> 6, c = flat & 63;     // c multiple of 8
    const unsigned short* p = base + (size_t)r * 1536 + c;
    uint4 q8 = *reinterpret_cast<const uint4*>(p);
    uint4 k8 = *reinterpret_cast<const uint4*>(p + 64);
    uint4 v8 = *reinterpret_cast<const uint4*>(p + 128);
    int us = r * 64 + (c ^ ((r & 7) << 3));
    *reinterpret_cast<uint4*>(&Qs[us]) = q8;
    *reinterpret_cast<uint4*>(&Ks[us]) = k8;
    const unsigned short* ve = reinterpret_cast<const unsigned short*>(&v8);
#pragma unroll
    for (int j = 0; j < 8; ++j) {
      int d = c + j;
      Vs[d * 64 + (r ^ ((d & 7) << 3))] = ve[j];
    }
  }
  __syncthreads();

  // S = Q @ K^T
  f32x4 sacc[4] = {};
#pragma unroll
  for (int kk = 0; kk < 64; kk += 32) {
    const int kb = kk + (lane >> 4) * 8;
    const int rq = wave * 16 + (lane & 15);
    bf16x8 aq = ld_frag(&Qs[rq * 64 + (kb ^ ((rq & 7) << 3))]);
#pragma unroll
    for (int n = 0; n < 4; ++n) {
      const int rk = n * 16 + (lane & 15);
      bf16x8 bk = ld_frag(&Ks[rk * 64 + (kb ^ ((rk & 7) << 3))]);
      sacc[n] = __builtin_amdgcn_mfma_f32_16x16x32_bf16(aq, bk, sacc[n], 0, 0, 0);
    }
  }
  // softmax (scale 1/8); lane rows wave*16+(lane>>4)*4+r, cols n*16+(lane&15)
#pragma unroll
  for (int r = 0; r < 4; ++r) {
    float mx = -1e30f;
#pragma unroll
    for (int n = 0; n < 4; ++n) mx = fmaxf(mx, sacc[n][r]);
#pragma unroll
    for (int msk = 1; msk < 16; msk <<= 1) mx = fmaxf(mx, __shfl_xor(mx, msk));
    float sum = 0.f;
#pragma unroll
    for (int n = 0; n < 4; ++n) {
      float e = __expf((sacc[n][r] - mx) * 0.125f);
      sacc[n][r] = e;
      sum += e;
    }
#pragma unroll
    for (int msk = 1; msk < 16; msk <<= 1) sum += __shfl_xor(sum, msk);
    const float inv = 1.f / sum;
    const int row = wave * 16 + (lane >> 4) * 4 + r;
#pragma unroll
    for (int n = 0; n < 4; ++n) {
      int col = n * 16 + (lane & 15);
      Ps[row * 64 + (col ^ ((row & 7) << 3))] = f2bf(sacc[n][r] * inv);
    }
  }
  __syncthreads();

  // O = P @ V
  f32x4 oacc[4] = {};
#pragma unroll
  for (int kk = 0; kk < 64; kk += 32) {
    const int kb = kk + (lane >> 4) * 8;
    const int rp = wave * 16 + (lane & 15);
    bf16x8 ap = ld_frag(&Ps[rp * 64 + (kb ^ ((rp & 7) << 3))]);
#pragma unroll
    for (int n = 0; n < 4; ++n) {
      const int rv = n * 16 + (lane & 15);
      bf16x8 bv = ld_frag(&Vs[rv * 64 + (kb ^ ((rv & 7) << 3))]);
      oacc[n] = __builtin_amdgcn_mfma_f32_16x16x32_bf16(ap, bv, oacc[n], 0, 0, 0);
    }
  }
#pragma unroll
  for (int n = 0; n < 4; ++n) {
    const int col = n * 16 + (lane & 15);
#pragma unroll
    for (int r = 0; r < 4; ++r) {
      const int row = wave * 16 + (lane >> 4) * 4 + r;
      out[(tok0 + row) * 512 + h * 64 + col] = f2bf(oacc[n][r]);
    }
  }
}

// ---------------- LayerNorm over D=512 (bf16 in), one wave per token -----
template <bool OUT_F32>
__global__ __launch_bounds__(256) void ln_kernel(
    const unsigned short* __restrict__ in, const float* __restrict__ gam,
    const float* __restrict__ bet, void* __restrict__ out) {
  const int wave = threadIdx.x >> 6, lane = threadIdx.x & 63;
  const size_t tok = (size_t)blockIdx.x * 4 + wave;
  const unsigned short* p = in + tok * DIM + lane * 8;
  uint4 raw = *reinterpret_cast<const uint4*>(p);
  const unsigned short* us = reinterpret_cast<const unsigned short*>(&raw);
  float x[8];
#pragma unroll
  for (int j = 0; j < 8; ++j) x[j] = bf2f(us[j]);
  float s = 0.f;
#pragma unroll
  for (int j = 0; j < 8; ++j) s += x[j];
#pragma unroll
  for (int m = 1; m < 64; m <<= 1) s += __shfl_xor(s, m);
  const float mean = s * (1.f / 512.f);
  float vr = 0.f;
#pragma unroll
  for (int j = 0; j < 8; ++j) { x[j] -= mean; vr += x[j] * x[j]; }
#pragma unroll
  for (int m = 1; m < 64; m <<= 1) vr += __shfl_xor(vr, m);
  const float rs = rsqrtf(vr * (1.f / 512.f) + 1e-5f);
  alignas(16) float gv[8], bv[8];
  *reinterpret_cast<float4*>(&gv[0]) = *reinterpret_cast<const float4*>(gam + lane * 8);
  *reinterpret_cast<float4*>(&gv[4]) = *reinterpret_cast<const float4*>(gam + lane * 8 + 4);
  *reinterpret_cast<float4*>(&bv[0]) = *reinterpret_cast<const float4*>(bet + lane * 8);
  *reinterpret_cast<float4*>(&bv[4]) = *reinterpret_cast<const float4*>(bet + lane * 8 + 4);
  if constexpr (OUT_F32) {
    alignas(16) float o[8];
#pragma unroll
    for (int j = 0; j < 8; ++j) o[j] = x[j] * rs * gv[j] + bv[j];
    float* q = reinterpret_cast<float*>(out) + tok * DIM + lane * 8;
    *reinterpret_cast<float4*>(q) = *reinterpret_cast<const float4*>(&o[0]);
    *reinterpret_cast<float4*>(q + 4) = *reinterpret_cast<const float4*>(&o[4]);
  } else {
    union { unsigned short us[8]; uint4 u; } rr;
#pragma unroll
    for (int j = 0; j < 8; ++j) rr.us[j] = f2bf(x[j] * rs * gv[j] + bv[j]);
    unsigned short* q = reinterpret_cast<unsigned short*>(out) + tok * DIM + lane * 8;
    *reinterpret_cast<uint4*>(q) = rr.u;
  }
}

// -------------------------------------------------------------------------
extern "C" void kernel_launch(void* const* d_in, const int* in_sizes, int n_in,
                              void* d_out, int out_size, void* d_ws, size_t ws_size,
                              hipStream_t stream) {
  const float* x          = (const float*)d_in[0];
  const float* w_qkv      = (const float*)d_in[1];
  const float* b_qkv      = (const float*)d_in[2];
  const float* w_proj     = (const float*)d_in[3];
  const float* b_proj     = (const float*)d_in[4];
  const float* ln1_g      = (const float*)d_in[5];
  const float* ln1_b      = (const float*)d_in[6];
  const float* ln2_g      = (const float*)d_in[7];
  const float* ln2_b      = (const float*)d_in[8];
  const float* w_ffn1     = (const float*)d_in[9];
  const float* b_ffn1     = (const float*)d_in[10];
  const float* w_ffn2     = (const float*)d_in[11];
  const float* b_ffn2     = (const float*)d_in[12];
  const float* attn_scale = (const float*)d_in[13];
  const float* attn_bias  = (const float*)d_in[14];
  const float* mlp_scale  = (const float*)d_in[15];
  const float* mlp_bias   = (const float*)d_in[16];

  char* ws = (char*)d_ws;
  const size_t MiB = 1024ull * 1024ull;
  // ws plan (peak 64 MiB):
  unsigned short* xt    = (unsigned short*)(ws + 0);        // [0,32M)  steps 1-4
  unsigned short* qkvH  = (unsigned short*)(ws + 32 * MiB); // [32,56M) per-chunk
  unsigned short* ares  = (unsigned short*)(ws + 32 * MiB); // [32,64M) steps 4-5
  unsigned short* gbuf  = (unsigned short*)(ws + 0);        // [0,64M)  steps 6-8
  float*          outt  = (float*)(ws + 0);                 // [0,64M)  steps 9-10
  // d_out doubles as scratch (fully rewritten at step 10):
  unsigned short* attnO = (unsigned short*)d_out;                       // steps 3-4
  unsigned short* hbuf  = (unsigned short*)d_out;                       // steps 5-8
  unsigned short* mres  = (unsigned short*)d_out + (size_t)NTOK * 512;  // steps 8-9
  float* outp = (float*)d_out;

  dim3 B256(256);
  // 1. x (B,512,4096) f32 -> xt (B,4096,512) bf16
  transpose_kernel<true><<<dim3(64, 8, 8), B256, 0, stream>>>(x, xt, 512, 4096);
  // 2+3. per-chunk: qkvH = xt_chunk @ w_qkv + b_qkv; attnO_chunk = blockattn(qkvH)
  for (int c = 0; c < NCHUNK; ++c) {
    gemm_kernel<false><<<dim3(12, MCH / 128), B256, 0, stream>>>(
        xt + (size_t)c * MCH * 512, w_qkv, b_qkv, nullptr, nullptr, nullptr,
        qkvH, MCH, 1536, 512);
    attn_kernel<<<dim3(MCH / 64 * 8), B256, 0, stream>>>(
        qkvH, attnO + (size_t)c * MCH * 512);
  }
  // 4. ares = (attnO @ w_proj + b_proj) * attn_scale + attn_bias + xt
  gemm_kernel<true><<<dim3(4, 256), B256, 0, stream>>>(
      attnO, w_proj, b_proj, attn_scale, attn_bias, xt, ares, NTOK, 512, 512);
  // 5. h = LN1(ares)   (h lives in d_out lo)
  ln_kernel<false><<<dim3(8192), B256, 0, stream>>>(ares, ln1_g, ln1_b, hbuf);
  // 6+7. g = ffn1+glu(h)
  ffn1glu_kernel<<<dim3(16, 256), B256, 0, stream>>>(hbuf, w_ffn1, b_ffn1, gbuf);
  // 8. mres = (g @ w_ffn2 + b_ffn2) * mlp_scale + mlp_bias + h
  gemm_kernel<true><<<dim3(4, 256), B256, 0, stream>>>(
      gbuf, w_ffn2, b_ffn2, mlp_scale, mlp_bias, hbuf, mres, NTOK, 512, 1024);
  // 9. outt = LN2(mres)  f32
  ln_kernel<true><<<dim3(8192), B256, 0, stream>>>(mres, ln2_g, ln2_b, outt);
  // 10. outt (B,4096,512) -> d_out (B,512,4096)
  transpose_kernel<false><<<dim3(8, 64, 8), B256, 0, stream>>>(outt, d_out, 4096, 512);
}

// Round 3
// 412.927 us; speedup vs baseline: 2.2107x; 2.2107x over previous
//
#include <hip/hip_runtime.h>

#define DIM   512
#define LSEQ  4096
#define BATCH 8
#define NTOK  (BATCH * LSEQ)   // 32768
#define NCHUNK 4
#define MCH   (NTOK / NCHUNK)  // 8192 tokens per chunk (qkv/attn)
#define FCH   (NTOK / 2)       // 16384 tokens per chunk (ffn)

typedef __bf16 bf16_t;
typedef bf16_t bf16x8 __attribute__((ext_vector_type(8)));
typedef float  f32x4  __attribute__((ext_vector_type(4)));

__device__ __forceinline__ unsigned short f2bf(float f) {
  unsigned u = __builtin_bit_cast(unsigned, f);
  unsigned r = u + 0x7fffu + ((u >> 16) & 1u);   // RNE
  return (unsigned short)(r >> 16);
}
__device__ __forceinline__ float bf2f(unsigned short s) {
  return __builtin_bit_cast(float, ((unsigned)s) << 16);
}
__device__ __forceinline__ bf16x8 ld_frag(const unsigned short* p) {
  uint4 v = *reinterpret_cast<const uint4*>(p);
  return __builtin_bit_cast(bf16x8, v);
}
// async global->LDS, 16B per lane; LDS dest = wave-uniform base + lane*16
__device__ __forceinline__ void gload16(const unsigned short* g, unsigned short* l) {
  __builtin_amdgcn_global_load_lds(
      (const __attribute__((address_space(1))) unsigned int*)(const void*)g,
      (__attribute__((address_space(3))) unsigned int*)(void*)l, 16, 0, 0);
}

// ---------------- weight prep: W[K][N] f32 -> tiles [kt][nb][128][64] bf16,
// pre-swizzled so a flat copy into LDS yields Bs[nn*64 + (k ^ ((nn&7)<<3))].
__global__ __launch_bounds__(256) void prep_w(
    const float* __restrict__ W, unsigned short* __restrict__ out,
    int N, int NB, int ffn1) {
  const int idx = blockIdx.x * 256 + threadIdx.x;   // K*N/8 threads
  const int j0 = (idx & 7) * 8;
  const int nn = (idx >> 3) & 127;
  const int nbkt = idx >> 10;          // = kt*NB + nb
  const int nb = nbkt % NB;
  const int kt = nbkt / NB;
  int wcol;
  if (ffn1) {
    int isg = (nn >> 5) & 1;
    int gcol = ((nn >> 6) << 5) + (((nn >> 4) & 1) << 4) + (nn & 15);
    wcol = isg * 1024 + nb * 64 + gcol;
  } else {
    wcol = nb * 128 + nn;
  }
  const int s = (nn & 7) << 3;
  union { unsigned short us[8]; uint4 u; } r;
#pragma unroll
  for (int t = 0; t < 8; ++t) {
    int row = kt * 64 + ((j0 ^ s) + t);
    r.us[t] = f2bf(W[(size_t)row * N + wcol]);
  }
  *reinterpret_cast<uint4*>(out + (size_t)nbkt * 8192 + nn * 64 + j0) = r.u;
}

// ---------------- transpose: in[B][R][C] f32 -> out[B][C][R] (f32 or bf16)
template <bool OUT_BF16>
__global__ __launch_bounds__(256) void transpose_kernel(
    const float* __restrict__ in, void* __restrict__ out, int R, int C) {
  __shared__ float tile[64][65];
  const int b = blockIdx.z;
  const int r0 = blockIdx.y * 64, c0 = blockIdx.x * 64;
  const float* ip = in + ((size_t)b * R + r0) * C + c0;
#pragma unroll
  for (int i = 0; i < 16; ++i) {
    int flat = i * 256 + threadIdx.x;
    int r = flat >> 6, c = flat & 63;
    tile[r][c] = ip[(size_t)r * C + c];
  }
  __syncthreads();
#pragma unroll
  for (int i = 0; i < 16; ++i) {
    int flat = i * 256 + threadIdx.x;
    int r = flat >> 6, c = flat & 63;   // r = col-of-input
    size_t idx = ((size_t)b * C + c0 + r) * R + r0 + c;
    if constexpr (OUT_BF16)
      reinterpret_cast<unsigned short*>(out)[idx] = f2bf(tile[c][r]);
    else
      reinterpret_cast<float*>(out)[idx] = tile[c][r];
  }
}

// ---------------- GEMM: C = A[MxK](bf16) @ W[KxN] + bias
//                  optionally (*scale + bias2 + res). Out bf16.
// Wt: pre-swizzled tiles. 1-D grid, XCD-chunk-swizzled (nwg % 8 == 0).
template <bool SCALERES>
__global__ __launch_bounds__(256) void gemm_kernel(
    const unsigned short* __restrict__ A, const unsigned short* __restrict__ Wt,
    const float* __restrict__ bias, const float* __restrict__ scale,
    const float* __restrict__ bias2, const unsigned short* __restrict__ res,
    unsigned short* __restrict__ Cout, int N, int K, int nxb) {
  __shared__ unsigned short As[128 * 64];
  __shared__ unsigned short Bs[128 * 64];
  const int tid = threadIdx.x, lane = tid & 63, wave = tid >> 6;
  const int wm = wave >> 1, wn = wave & 1;
  const int cpx = gridDim.x >> 3;
  const int sid = (blockIdx.x & 7) * cpx + (blockIdx.x >> 3);
  const int by = sid / nxb, bx = sid - by * nxb;
  const int row0 = by * 128, col0 = bx * 128;

  // per-lane staging sources (A: inverse-swizzled; B: pre-swizzled flat)
  const unsigned short* abase =
      A + (size_t)(row0 + (lane >> 3)) * K + 8 * ((lane & 7) ^ (lane >> 3));
  const unsigned short* bbase = Wt + (size_t)bx * 8192 + lane * 8;
  const size_t bstride = (size_t)nxb * 8192;

  f32x4 acc[4][4] = {};

  for (int kt = 0; kt < K; kt += 64) {
#pragma unroll
    for (int c = 0; c < 4; ++c) {
      const int ch = wave * 4 + c;
      gload16(abase + (size_t)(ch * 8) * K + kt, &As[ch * 512]);
      gload16(bbase + (size_t)(kt >> 6) * bstride + ch * 512, &Bs[ch * 512]);
    }
    __syncthreads();
#pragma unroll
    for (int kk = 0; kk < 64; kk += 32) {
      const int kb = kk + (lane >> 4) * 8;
      bf16x8 af[4], bfr[4];
#pragma unroll
      for (int m = 0; m < 4; ++m) {
        int r = wm * 64 + m * 16 + (lane & 15);
        af[m] = ld_frag(&As[r * 64 + (kb ^ ((r & 7) << 3))]);
      }
#pragma unroll
      for (int n = 0; n < 4; ++n) {
        int r = wn * 64 + n * 16 + (lane & 15);
        bfr[n] = ld_frag(&Bs[r * 64 + (kb ^ ((r & 7) << 3))]);
      }
#pragma unroll
      for (int m = 0; m < 4; ++m)
#pragma unroll
        for (int n = 0; n < 4; ++n)
          acc[m][n] = __builtin_amdgcn_mfma_f32_16x16x32_bf16(
              af[m], bfr[n], acc[m][n], 0, 0, 0);
    }
    __syncthreads();
  }
#pragma unroll
  for (int m = 0; m < 4; ++m) {
#pragma unroll
    for (int n = 0; n < 4; ++n) {
      const int col = col0 + wn * 64 + n * 16 + (lane & 15);
      const float b1 = bias[col];
      float sc = 1.f, b2 = 0.f;
      if constexpr (SCALERES) { sc = scale[col]; b2 = bias2[col]; }
#pragma unroll
      for (int r = 0; r < 4; ++r) {
        const int row = row0 + wm * 64 + m * 16 + (lane >> 4) * 4 + r;
        float v = acc[m][n][r] + b1;
        if constexpr (SCALERES) {
          v = v * sc + b2;
          v += bf2f(res[(size_t)row * N + col]);
        }
        Cout[(size_t)row * N + col] = f2bf(v);
      }
    }
  }
}

// ---------------- FFN1 + GLU fused (pre-permuted weight tiles)
__global__ __launch_bounds__(256) void ffn1glu_kernel(
    const unsigned short* __restrict__ A, const unsigned short* __restrict__ Wt,
    const float* __restrict__ b1, unsigned short* __restrict__ g, int nxb) {
  __shared__ unsigned short As[128 * 64];
  __shared__ unsigned short Bs[128 * 64];
  const int tid = threadIdx.x, lane = tid & 63, wave = tid >> 6;
  const int wm = wave >> 1, wn = wave & 1;
  const int cpx = gridDim.x >> 3;
  const int sid = (blockIdx.x & 7) * cpx + (blockIdx.x >> 3);
  const int by = sid / nxb, bx = sid - by * nxb;
  const int row0 = by * 128, c0 = bx * 64;
  const int K = 512;

  const unsigned short* abase =
      A + (size_t)(row0 + (lane >> 3)) * K + 8 * ((lane & 7) ^ (lane >> 3));
  const unsigned short* bbase = Wt + (size_t)bx * 8192 + lane * 8;
  const size_t bstride = (size_t)nxb * 8192;

  f32x4 acc[4][4] = {};

  for (int kt = 0; kt < K; kt += 64) {
#pragma unroll
    for (int c = 0; c < 4; ++c) {
      const int ch = wave * 4 + c;
      gload16(abase + (size_t)(ch * 8) * K + kt, &As[ch * 512]);
      gload16(bbase + (size_t)(kt >> 6) * bstride + ch * 512, &Bs[ch * 512]);
    }
    __syncthreads();
#pragma unroll
    for (int kk = 0; kk < 64; kk += 32) {
      const int kb = kk + (lane >> 4) * 8;
      bf16x8 af[4], bfr[4];
#pragma unroll
      for (int m = 0; m < 4; ++m) {
        int r = wm * 64 + m * 16 + (lane & 15);
        af[m] = ld_frag(&As[r * 64 + (kb ^ ((r & 7) << 3))]);
      }
#pragma unroll
      for (int n = 0; n < 4; ++n) {
        int r = wn * 64 + n * 16 + (lane & 15);
        bfr[n] = ld_frag(&Bs[r * 64 + (kb ^ ((r & 7) << 3))]);
      }
#pragma unroll
      for (int m = 0; m < 4; ++m)
#pragma unroll
        for (int n = 0; n < 4; ++n)
          acc[m][n] = __builtin_amdgcn_mfma_f32_16x16x32_bf16(
              af[m], bfr[n], acc[m][n], 0, 0, 0);
    }
    __syncthreads();
  }
  // acc[m][n] (out) pairs with acc[m][n+2] (gate), n in {0,1}
#pragma unroll
  for (int m = 0; m < 4; ++m) {
#pragma unroll
    for (int n = 0; n < 2; ++n) {
      const int gc = c0 + wn * 32 + n * 16 + (lane & 15);
      const float bo = b1[gc];
      const float bg = b1[1024 + gc];
#pragma unroll
      for (int r = 0; r < 4; ++r) {
        const int row = row0 + wm * 64 + m * 16 + (lane >> 4) * 4 + r;
        float o  = acc[m][n][r] + bo;
        float ga = acc[m][n + 2][r] + bg;
        float s  = ga / (1.f + __expf(-ga));
        g[(size_t)row * 1024 + gc] = f2bf(o * s);
      }
    }
  }
}

// ---------------- block-local attention, one (blk-of-64-tokens, head) per WG
__global__ __launch_bounds__(256) void attn_kernel(
    const unsigned short* __restrict__ qkv, unsigned short* __restrict__ out) {
  __shared__ unsigned short Qs[64 * 64];
  __shared__ unsigned short Ks[64 * 64];
  __shared__ unsigned short Vs[64 * 64];  // [d][key]
  __shared__ unsigned short Ps[64 * 64];
  const int id = blockIdx.x;
  const int h = id & 7, blk = id >> 3;
  const size_t tok0 = (size_t)blk * 64;
  const unsigned short* base = qkv + tok0 * 1536 + h * 192;
  const int tid = threadIdx.x, lane = tid & 63, wave = tid >> 6;

#pragma unroll
  for (int i = 0; i < 2; ++i) {
    int flat = i * 2048 + tid * 8;
    int r = flat >> 6, c = flat & 63;
    const unsigned short* p = base + (size_t)r * 1536 + c;
    uint4 q8 = *reinterpret_cast<const uint4*>(p);
    uint4 k8 = *reinterpret_cast<const uint4*>(p + 64);
    uint4 v8 = *reinterpret_cast<const uint4*>(p + 128);
    int us = r * 64 + (c ^ ((r & 7) << 3));
    *reinterpret_cast<uint4*>(&Qs[us]) = q8;
    *reinterpret_cast<uint4*>(&Ks[us]) = k8;
    const unsigned short* ve = reinterpret_cast<const unsigned short*>(&v8);
#pragma unroll
    for (int j = 0; j < 8; ++j) {
      int d = c + j;
      Vs[d * 64 + (r ^ ((d & 7) << 3))] = ve[j];
    }
  }
  __syncthreads();

  f32x4 sacc[4] = {};
#pragma unroll
  for (int kk = 0; kk < 64; kk += 32) {
    const int kb = kk + (lane >> 4) * 8;
    const int rq = wave * 16 + (lane & 15);
    bf16x8 aq = ld_frag(&Qs[rq * 64 + (kb ^ ((rq & 7) << 3))]);
#pragma unroll
    for (int n = 0; n < 4; ++n) {
      const int rk = n * 16 + (lane & 15);
      bf16x8 bk = ld_frag(&Ks[rk * 64 + (kb ^ ((rk & 7) << 3))]);
      sacc[n] = __builtin_amdgcn_mfma_f32_16x16x32_bf16(aq, bk, sacc[n], 0, 0, 0);
    }
  }
#pragma unroll
  for (int r = 0; r < 4; ++r) {
    float mx = -1e30f;
#pragma unroll
    for (int n = 0; n < 4; ++n) mx = fmaxf(mx, sacc[n][r]);
#pragma unroll
    for (int msk = 1; msk < 16; msk <<= 1) mx = fmaxf(mx, __shfl_xor(mx, msk));
    float sum = 0.f;
#pragma unroll
    for (int n = 0; n < 4; ++n) {
      float e = __expf((sacc[n][r] - mx) * 0.125f);
      sacc[n][r] = e;
      sum += e;
    }
#pragma unroll
    for (int msk = 1; msk < 16; msk <<= 1) sum += __shfl_xor(sum, msk);
    const float inv = 1.f / sum;
    const int row = wave * 16 + (lane >> 4) * 4 + r;
#pragma unroll
    for (int n = 0; n < 4; ++n) {
      int col = n * 16 + (lane & 15);
      Ps[row * 64 + (col ^ ((row & 7) << 3))] = f2bf(sacc[n][r] * inv);
    }
  }
  __syncthreads();

  f32x4 oacc[4] = {};
#pragma unroll
  for (int kk = 0; kk < 64; kk += 32) {
    const int kb = kk + (lane >> 4) * 8;
    const int rp = wave * 16 + (lane & 15);
    bf16x8 ap = ld_frag(&Ps[rp * 64 + (kb ^ ((rp & 7) << 3))]);
#pragma unroll
    for (int n = 0; n < 4; ++n) {
      const int rv = n * 16 + (lane & 15);
      bf16x8 bv = ld_frag(&Vs[rv * 64 + (kb ^ ((rv & 7) << 3))]);
      oacc[n] = __builtin_amdgcn_mfma_f32_16x16x32_bf16(ap, bv, oacc[n], 0, 0, 0);
    }
  }
#pragma unroll
  for (int n = 0; n < 4; ++n) {
    const int col = n * 16 + (lane & 15);
#pragma unroll
    for (int r = 0; r < 4; ++r) {
      const int row = wave * 16 + (lane >> 4) * 4 + r;
      out[(tok0 + row) * 512 + h * 64 + col] = f2bf(oacc[n][r]);
    }
  }
}

// ---------------- LayerNorm over D=512 (bf16 in), one wave per token -----
template <bool OUT_F32>
__global__ __launch_bounds__(256) void ln_kernel(
    const unsigned short* __restrict__ in, const float* __restrict__ gam,
    const float* __restrict__ bet, void* __restrict__ out) {
  const int wave = threadIdx.x >> 6, lane = threadIdx.x & 63;
  const size_t tok = (size_t)blockIdx.x * 4 + wave;
  const unsigned short* p = in + tok * DIM + lane * 8;
  uint4 raw = *reinterpret_cast<const uint4*>(p);
  const unsigned short* us = reinterpret_cast<const unsigned short*>(&raw);
  float x[8];
#pragma unroll
  for (int j = 0; j < 8; ++j) x[j] = bf2f(us[j]);
  float s = 0.f;
#pragma unroll
  for (int j = 0; j < 8; ++j) s += x[j];
#pragma unroll
  for (int m = 1; m < 64; m <<= 1) s += __shfl_xor(s, m);
  const float mean = s * (1.f / 512.f);
  float vr = 0.f;
#pragma unroll
  for (int j = 0; j < 8; ++j) { x[j] -= mean; vr += x[j] * x[j]; }
#pragma unroll
  for (int m = 1; m < 64; m <<= 1) vr += __shfl_xor(vr, m);
  const float rs = rsqrtf(vr * (1.f / 512.f) + 1e-5f);
  alignas(16) float gv[8], bv[8];
  *reinterpret_cast<float4*>(&gv[0]) = *reinterpret_cast<const float4*>(gam + lane * 8);
  *reinterpret_cast<float4*>(&gv[4]) = *reinterpret_cast<const float4*>(gam + lane * 8 + 4);
  *reinterpret_cast<float4*>(&bv[0]) = *reinterpret_cast<const float4*>(bet + lane * 8);
  *reinterpret_cast<float4*>(&bv[4]) = *reinterpret_cast<const float4*>(bet + lane * 8 + 4);
  if constexpr (OUT_F32) {
    alignas(16) float o[8];
#pragma unroll
    for (int j = 0; j < 8; ++j) o[j] = x[j] * rs * gv[j] + bv[j];
    float* q = reinterpret_cast<float*>(out) + tok * DIM + lane * 8;
    *reinterpret_cast<float4*>(q) = *reinterpret_cast<const float4*>(&o[0]);
    *reinterpret_cast<float4*>(q + 4) = *reinterpret_cast<const float4*>(&o[4]);
  } else {
    union { unsigned short us[8]; uint4 u; } rr;
#pragma unroll
    for (int j = 0; j < 8; ++j) rr.us[j] = f2bf(x[j] * rs * gv[j] + bv[j]);
    unsigned short* q = reinterpret_cast<unsigned short*>(out) + tok * DIM + lane * 8;
    *reinterpret_cast<uint4*>(q) = rr.u;
  }
}

// -------------------------------------------------------------------------
extern "C" void kernel_launch(void* const* d_in, const int* in_sizes, int n_in,
                              void* d_out, int out_size, void* d_ws, size_t ws_size,
                              hipStream_t stream) {
  const float* x          = (const float*)d_in[0];
  const float* w_qkv      = (const float*)d_in[1];
  const float* b_qkv      = (const float*)d_in[2];
  const float* w_proj     = (const float*)d_in[3];
  const float* b_proj     = (const float*)d_in[4];
  const float* ln1_g      = (const float*)d_in[5];
  const float* ln1_b      = (const float*)d_in[6];
  const float* ln2_g      = (const float*)d_in[7];
  const float* ln2_b      = (const float*)d_in[8];
  const float* w_ffn1     = (const float*)d_in[9];
  const float* b_ffn1     = (const float*)d_in[10];
  const float* w_ffn2     = (const float*)d_in[11];
  const float* b_ffn2     = (const float*)d_in[12];
  const float* attn_scale = (const float*)d_in[13];
  const float* attn_bias  = (const float*)d_in[14];
  const float* mlp_scale  = (const float*)d_in[15];
  const float* mlp_bias   = (const float*)d_in[16];

  char* ws = (char*)d_ws;
  const size_t MiB = 1024ull * 1024ull;
  // ws plan (peak 64 MiB):
  unsigned short* wqkvT  = (unsigned short*)(ws + 0);            // 1.5 MiB, live ->step8
  unsigned short* wprojT = (unsigned short*)(ws + 3 * MiB / 2);  // 0.5 MiB
  unsigned short* wffn1T = (unsigned short*)(ws + 2 * MiB);      // 2 MiB
  unsigned short* wffn2T = (unsigned short*)(ws + 4 * MiB);      // 1 MiB
  unsigned short* xt     = (unsigned short*)(ws + 5 * MiB);      // 32 MiB, steps 1-4
  unsigned short* qkvH   = (unsigned short*)(ws + 37 * MiB);     // 24 MiB, chunk loop
  unsigned short* gbufC  = (unsigned short*)(ws + 5 * MiB);      // 32 MiB, steps 6-8 (xt dead)
  float*          outt   = (float*)(ws + 0);                     // 64 MiB, steps 9-10
  // d_out doubles as scratch (fully rewritten at step 10):
  unsigned short* attnO = (unsigned short*)d_out;                       // steps 3-4
  unsigned short* ares  = (unsigned short*)d_out + (size_t)NTOK * 512;  // steps 4-5
  unsigned short* hbuf  = (unsigned short*)d_out;                       // steps 5-8
  unsigned short* mres  = (unsigned short*)d_out + (size_t)NTOK * 512;  // steps 8-9

  dim3 B256(256);
  // 0. weight prep (bf16, transposed, swizzled, consumption order)
  prep_w<<<dim3(384), B256, 0, stream>>>(w_qkv,  wqkvT,  1536, 12, 0);
  prep_w<<<dim3(128), B256, 0, stream>>>(w_proj, wprojT,  512,  4, 0);
  prep_w<<<dim3(512), B256, 0, stream>>>(w_ffn1, wffn1T, 2048, 16, 1);
  prep_w<<<dim3(256), B256, 0, stream>>>(w_ffn2, wffn2T,  512,  4, 0);
  // 1. x (B,512,4096) f32 -> xt (B,4096,512) bf16
  transpose_kernel<true><<<dim3(64, 8, 8), B256, 0, stream>>>(x, xt, 512, 4096);
  // 2+3. per-chunk: qkvH = xt_chunk @ w_qkv + b_qkv; attnO_chunk = blockattn
  for (int c = 0; c < NCHUNK; ++c) {
    gemm_kernel<false><<<dim3(12 * (MCH / 128)), B256, 0, stream>>>(
        xt + (size_t)c * MCH * 512, wqkvT, b_qkv, nullptr, nullptr, nullptr,
        qkvH, 1536, 512, 12);
    attn_kernel<<<dim3(MCH / 64 * 8), B256, 0, stream>>>(
        qkvH, attnO + (size_t)c * MCH * 512);
  }
  // 4. ares = (attnO @ w_proj + b_proj) * attn_scale + attn_bias + xt
  gemm_kernel<true><<<dim3(4 * (NTOK / 128)), B256, 0, stream>>>(
      attnO, wprojT, b_proj, attn_scale, attn_bias, xt, ares, 512, 512, 4);
  // 5. h = LN1(ares)
  ln_kernel<false><<<dim3(NTOK / 4), B256, 0, stream>>>(ares, ln1_g, ln1_b, hbuf);
  // 6-8. per half: g = ffn1+glu(h); mres = (g @ w_ffn2 + b) * s + b2 + h
  for (int c = 0; c < 2; ++c) {
    ffn1glu_kernel<<<dim3(16 * (FCH / 128)), B256, 0, stream>>>(
        hbuf + (size_t)c * FCH * 512, wffn1T, b_ffn1, gbufC, 16);
    gemm_kernel<true><<<dim3(4 * (FCH / 128)), B256, 0, stream>>>(
        gbufC, wffn2T, b_ffn2, mlp_scale, mlp_bias, hbuf + (size_t)c * FCH * 512,
        mres + (size_t)c * FCH * 512, 512, 1024, 4);
  }
  // 9. outt = LN2(mres)  f32
  ln_kernel<true><<<dim3(NTOK / 4), B256, 0, stream>>>(mres, ln2_g, ln2_b, outt);
  // 10. outt (B,4096,512) -> d_out (B,512,4096)
  transpose_kernel<false><<<dim3(8, 64, 8), B256, 0, stream>>>(outt, d_out, 4096, 512);
}